// Round 15
// baseline (3838.470 us; speedup 1.0000x reference)
//
#include <hip/hip_runtime.h>
#include <hip/hip_bf16.h>

typedef unsigned short u16;
typedef unsigned int u32;
typedef unsigned long long u64;
typedef __attribute__((ext_vector_type(8))) short short8;
typedef __attribute__((ext_vector_type(4))) float floatx4;

#define I_DIM 256
#define H_DIM 1024
#define B_DIM 64
#define T_DIM 256
#define C_DIM 60
#define NWG   128
#define UPW   8      // hidden units per WG
#define SSTR  12     // scratch row stride (dwords): 16B-aligned, bank-spread
#define PACE  5      // post-publish visibility sleep, units of s_sleep(8) (~0.21us)
                     // FIXED: r19/r21 proved sub-visibility gaps trade cheap
                     // sleep for expensive repair storms. Do not trim.

// LDS layout (bytes)
#define LDS_W_OFF    0        // 2*40*4*16 frags * 16B = 81920
#define LDS_BIAS_OFF 81920    // 32*4 = 128
#define LDS_SCR_OFF  82048    // 8 waves * 32 rows * 12 dw * 4B = 12288
#define LDS_TOTAL    94336

// workspace layout (bytes)
#define WS_XSWZ   0u          // T*B*I bf16 = 8388608
#define WS_HSWZ   8388608u    // 256 slots * 64*1024 bf16 = 33554432 (never reused)
#define WS_HLAST  41943040u   // 64*1024 f32 = 262144

#define LSBM 0x0001000100010001ull

__device__ __forceinline__ u16 f2bf(float f) {
    u32 u = __float_as_uint(f);
    u32 r = (u + 0x7fffu + ((u >> 16) & 1u)) >> 16;
    return (u16)r;
}
__device__ __forceinline__ float fsig(float x) { return 1.0f / (1.0f + __expf(-x)); }
__device__ __forceinline__ float ftanh(float x) { return 2.0f * fsig(2.0f * x) - 1.0f; }

union hfrag { short8 s; u64 q[2]; };

// ---------------------------------------------------------------------------
// Pre-swizzle inputs [B][T][I] fp32 -> xswz[t] bf16 in MFMA-A-fragment layout:
// 16B unit index (per t): ((mt*8 + s)*4 + q)*16 + m  holds A[b=mt*16+m][k=s*32+q*8 .. +7]
// ---------------------------------------------------------------------------
extern "C" __global__ void prep_x(const float* __restrict__ in, u16* __restrict__ xswz) {
    int o = blockIdx.x * 256 + threadIdx.x;           // octet index, 524288 total
    int m = o & 15, q = (o >> 4) & 3, s = (o >> 6) & 7, mt = (o >> 9) & 3, t = o >> 11;
    int b = mt * 16 + m, k = s * 32 + q * 8;
    const float* src = in + ((size_t)(b * T_DIM + t)) * I_DIM + k;
    float4 v0 = *(const float4*)src;
    float4 v1 = *(const float4*)(src + 4);
    short8 val;
    val[0] = (short)f2bf(v0.x); val[1] = (short)f2bf(v0.y);
    val[2] = (short)f2bf(v0.z); val[3] = (short)f2bf(v0.w);
    val[4] = (short)f2bf(v1.x); val[5] = (short)f2bf(v1.y);
    val[6] = (short)f2bf(v1.z); val[7] = (short)f2bf(v1.w);
    *(short8*)(xswz + (size_t)o * 8) = val;
}

// ---------------------------------------------------------------------------
// Persistent LSTM scan (r24 = r23 STRUCTURE, LAUNCH-BOUNDS FIXED).
// r23 post-mortem: __launch_bounds__(512,2) is interpreted by hipcc with
// CUDA semantics (2nd arg = min BLOCKS per CU): 2 blocks x 8 waves / 4
// SIMDs = 4 waves/SIMD -> 128-VGPR cap -> a[40] (160 VGPR) spilled ->
// 4 GB scratch traffic, 3.8 ms. Cross-check: r17's (1024,1) showed
// VGPR_Count=64 (=256/4), r16's (512,2) showed cap 128. Fix: (512,1) ->
// 2 waves/SIMD -> 256-VGPR budget; a[40]+acc+addressing ~200 fits, zero
// spill. Structure (correctness-verified by r23's PASS):
//   SINGLE-WAVE STREAMS: 8 waves = 8 independent streams of 8 batches
//   (em-duplicated A-frag rows: lane m16 loads batch half*8+(m16&7); acc
//   rows 0..7 hold the half's batches). Full K per wave (8 x-sg + 32 h-sg,
//   80 MFMAs -- duplication makes 2x MFMA work, free at 8% MfmaUtil).
//   Wave-private LDS scratch guarded by own lgkmcnt(0): NO rendezvous,
//   no atomic, no cross-wave skew max. Pointwise on all 64 lanes.
// TIMING EQUILIBRIUM UNTOUCHED (session law r17/r18/r19/r21): FIXED
// PACE=5, ack-free tagged 2B publish (tag=(t%13)+1 per-u16 lsb, never
// 0=poison), throttled agent-scope repair, slot-per-step hswz, 2 waves/SIMD.
// ---------------------------------------------------------------------------
extern "C" __global__ void __launch_bounds__(512, 1) lstm_scan(
    const u16* __restrict__ xswz, u16* hswz,
    const float* __restrict__ Wih, const float* __restrict__ Whh,
    const float* __restrict__ bih, const float* __restrict__ bhh,
    float* hlast)
{
    extern __shared__ char lds[];
    u16*   Wlds = (u16*)(lds + LDS_W_OFF);
    float* bias = (float*)(lds + LDS_BIAS_OFF);

    const int j    = blockIdx.x;
    const int tid  = threadIdx.x;
    const int lane = tid & 63;
    const int w    = tid >> 6;    // wave = stream 0..7
    const int mt   = w >> 1;      // batch tile 0..3
    const int half = w & 1;       // half of tile (batches half*8 .. +7)
    float* scr = (float*)(lds + LDS_SCR_OFF) + w * (32 * SSTR);  // wave-private

    // ---- stage W slice into LDS, bf16, B-swizzled:
    // unit wu = ((nt*40 + sg)*4 + q)*16 + nn  holds W[r(nt,nn)][sg*32+q*8 .. +7]
    for (int i = 0; i < 10; ++i) {
        int wu = tid + i * 512;
        int nn = wu & 15, q = (wu >> 4) & 3, rest = wu >> 6;
        int sg = rest % 40, nt = rest / 40;
        int n = nt * 16 + nn;
        int g = n >> 3, uu = n & 7;
        int r = g * H_DIM + j * UPW + uu;
        int kb = sg * 32 + q * 8;
        const float* src = (kb < I_DIM) ? (Wih + (size_t)r * I_DIM + kb)
                                        : (Whh + (size_t)r * H_DIM + (kb - I_DIM));
        short8 val;
        #pragma unroll
        for (int e = 0; e < 8; ++e) val[e] = (short)f2bf(src[e]);
        *(short8*)(Wlds + (size_t)wu * 8) = val;
    }
    if (tid < 32) {
        int n = tid, g = n >> 3, uu = n & 7;
        int r = g * H_DIM + j * UPW + uu;
        bias[n] = bih[r] + bhh[r];
    }
    __syncthreads();   // last WG-wide barrier in the kernel

    const int m16 = lane & 15, q4 = lane >> 4;
    const int em  = half * 8 + (m16 & 7);     // A-row source, own half duplicated
    const int ib  = lane >> 3;                // pointwise: batch-in-8
    const int uu  = lane & 7;                 // pointwise: hidden unit
    float creg = 0.0f;                        // c state for this lane's item

    // A-frags: ss 0..7 = x (sg = ss), ss 8..39 = h (sgh = ss-8)
    hfrag a[40];

    // ---- prologue: loads for t=0 (slot 0 = h_0 = 0, no tag check at t=0)
    #pragma unroll
    for (int ss = 0; ss < 8; ++ss)
        a[ss].s = *(const short8*)(xswz
            + (size_t)(((mt * 8 + ss) * 4 + q4) * 16 + em) * 8);
    #pragma unroll
    for (int ss = 8; ss < 40; ++ss)
        a[ss].s = *(const short8*)(hswz
            + (size_t)(((mt * 32 + (ss - 8)) * 4 + q4) * 16 + em) * 8);

    for (int t = 0; t < T_DIM; ++t) {
        const u16* hbase = hswz + (size_t)t * (B_DIM * H_DIM);   // fresh slot
        u16*       hnext = hswz + (size_t)(t + 1) * (B_DIM * H_DIM);
        const u16* xnext = xswz + (size_t)(t + 1) * (B_DIM * I_DIM);
        const int  En    = (t % 13) + 1;          // tag nibble, never 0
        const u64  Eq    = (u64)(En & 1) | ((u64)((En >> 1) & 1) << 16)
                         | ((u64)((En >> 2) & 1) << 32) | ((u64)((En >> 3) & 1) << 48);
        const int  Ep    = ((t + 1) % 13) + 1;

        // ---- x part: 16 MFMAs while h loads (still in flight) arrive
        floatx4 acc[2];
        acc[0] = (floatx4){0.f, 0.f, 0.f, 0.f};
        acc[1] = (floatx4){0.f, 0.f, 0.f, 0.f};
        #pragma unroll
        for (int ss = 0; ss < 8; ++ss) {
            #pragma unroll
            for (int nt = 0; nt < 2; ++nt) {
                short8 bv = *(const short8*)(Wlds
                    + (size_t)(((nt * 40 + ss) * 4 + q4) * 16 + m16) * 8);
                acc[nt] = __builtin_amdgcn_mfma_f32_16x16x32_bf16(
                    a[ss].s, bv, acc[nt], 0, 0, 0);
            }
        }

        // ---- validate h-frag tags; throttled agent-scope repair
        if (t > 0) {
            u32 mk = 0;
            #pragma unroll
            for (int ss = 8; ss < 40; ++ss)
                if ((((a[ss].q[0] ^ Eq) | (a[ss].q[1] ^ Eq)) & LSBM) != 0)
                    mk |= 1u << (ss - 8);
            int rounds = 0;
            while (__any(mk != 0)) {
                ++rounds;
                #pragma unroll
                for (int ss = 8; ss < 40; ++ss)
                    if ((mk >> (ss - 8)) & 1) {
                        const u64* pp = (const u64*)hbase
                            + (size_t)(((mt * 32 + (ss - 8)) * 4 + q4) * 16 + em) * 2;
                        a[ss].q[0] = __hip_atomic_load(pp,     __ATOMIC_RELAXED, __HIP_MEMORY_SCOPE_AGENT);
                        a[ss].q[1] = __hip_atomic_load(pp + 1, __ATOMIC_RELAXED, __HIP_MEMORY_SCOPE_AGENT);
                    }
                #pragma unroll
                for (int ss = 8; ss < 40; ++ss)
                    if (((mk >> (ss - 8)) & 1) &&
                        ((((a[ss].q[0] ^ Eq) | (a[ss].q[1] ^ Eq)) & LSBM) == 0))
                        mk &= ~(1u << (ss - 8));
                if (__any(mk != 0)) {
                    if (rounds < 4) __builtin_amdgcn_s_sleep(4);
                    else            __builtin_amdgcn_s_sleep(16);
                }
            }
        }

        // ---- h part: 64 MFMAs (32 h-sg x 2 ntiles), full K in this wave
        #pragma unroll
        for (int ss = 8; ss < 40; ++ss) {
            int sg = 8 + (ss - 8);
            #pragma unroll
            for (int nt = 0; nt < 2; ++nt) {
                short8 bv = *(const short8*)(Wlds
                    + (size_t)(((nt * 40 + sg) * 4 + q4) * 16 + m16) * 8);
                acc[nt] = __builtin_amdgcn_mfma_f32_16x16x32_bf16(
                    a[ss].s, bv, acc[nt], 0, 0, 0);
            }
        }

        // ---- stash C to wave-private scratch (no rendezvous, no atomic):
        // acc rows 0..7 hold the half's 8 batches (em-duplication) -> lanes
        // q4<2 store. scr[n*SSTR + b8], n = nt*16+m16.
        if (q4 < 2) {
            #pragma unroll
            for (int nt = 0; nt < 2; ++nt)
                *(floatx4*)(scr + (nt * 16 + m16) * SSTR + q4 * 4) = acc[nt];
        }
        asm volatile("s_waitcnt lgkmcnt(0)" ::: "memory");

        // ---- pointwise (all 64 lanes: 8 batches x 8 units), gates, c/h;
        // direct tagged 2B publish (contiguous 128B per wave)
        {
            float sv[4];
            #pragma unroll
            for (int g = 0; g < 4; ++g)
                sv[g] = bias[g * 8 + uu] + scr[(g * 8 + uu) * SSTR + ib];
            float ig = fsig(sv[0]), fg = fsig(sv[1]), gg = ftanh(sv[2]), og = fsig(sv[3]);
            float c = fg * creg + ig * gg;
            creg = c;
            float h = og * ftanh(c);
            if (t == T_DIM - 1) {
                hlast[(size_t)(mt * 16 + half * 8 + ib) * H_DIM + j * UPW + uu] = h;
            } else {
                u16 hb16 = (u16)((f2bf(h) & 0xFFFEu) | ((u32)(Ep >> (uu & 3)) & 1u));
                // unit octet ((mt*32 + (j>>2))*4 + (j&3))*16 + m, elem uu;
                // m = half*8+ib -> offset half*64 + lane
                u16* dst = hnext
                    + (size_t)((mt * 32 + (j >> 2)) * 4 + (j & 3)) * 128
                    + half * 64 + lane;
                __hip_atomic_store(dst, hb16, __ATOMIC_RELAXED,
                                   __HIP_MEMORY_SCOPE_AGENT);
            }
        }
        asm volatile("" ::: "memory");

        // ---- issue next step's loads: x now (tag-free), h after the
        // visibility sleep (sleep is free: co-resident wave uses the SIMD)
        if (t + 1 < T_DIM) {
            #pragma unroll
            for (int ss = 0; ss < 8; ++ss)
                a[ss].s = *(const short8*)(xnext
                    + (size_t)(((mt * 8 + ss) * 4 + q4) * 16 + em) * 8);
            for (int p = 0; p < PACE; ++p) __builtin_amdgcn_s_sleep(8);
            #pragma unroll
            for (int ss = 8; ss < 40; ++ss)
                a[ss].s = *(const short8*)(hnext
                    + (size_t)(((mt * 32 + (ss - 8)) * 4 + q4) * 16 + em) * 8);
        }
    }
}

// ---------------------------------------------------------------------------
// FC + log_softmax: one wave per batch row. logits[b][c] = h.fc_w[c] + fc_b[c]
// ---------------------------------------------------------------------------
extern "C" __global__ void fc_logsoftmax(const float* __restrict__ hlast,
                                         const float* __restrict__ fcw,
                                         const float* __restrict__ fcb,
                                         float* __restrict__ out)
{
    int b = blockIdx.x, c = threadIdx.x;  // 64 threads, 1 wave
    float acc = 0.0f;
    if (c < C_DIM) {
        const float* wr = fcw + (size_t)c * H_DIM;
        const float* hr = hlast + (size_t)b * H_DIM;
        for (int k = 0; k < H_DIM; k += 4) {
            float4 hv = *(const float4*)(hr + k);
            float4 wv = *(const float4*)(wr + k);
            acc += hv.x * wv.x + hv.y * wv.y + hv.z * wv.z + hv.w * wv.w;
        }
        acc += fcb[c];
    }
    float logit = (c < C_DIM) ? acc : -1e30f;
    float mx = logit;
    #pragma unroll
    for (int off = 32; off; off >>= 1) mx = fmaxf(mx, __shfl_xor(mx, off));
    float e = (c < C_DIM) ? expf(logit - mx) : 0.0f;
    float sum = e;
    #pragma unroll
    for (int off = 32; off; off >>= 1) sum += __shfl_xor(sum, off);
    if (c < C_DIM) out[b * C_DIM + c] = logit - mx - logf(sum);
}

extern "C" void kernel_launch(void* const* d_in, const int* in_sizes, int n_in,
                              void* d_out, int out_size, void* d_ws, size_t ws_size,
                              hipStream_t stream)
{
    const float* inputs = (const float*)d_in[0];
    const float* Wih    = (const float*)d_in[1];
    const float* Whh    = (const float*)d_in[2];
    const float* bih    = (const float*)d_in[3];
    const float* bhh    = (const float*)d_in[4];
    const float* fcw    = (const float*)d_in[5];
    const float* fcb    = (const float*)d_in[6];
    float* out = (float*)d_out;

    char* ws = (char*)d_ws;
    u16*   xswz  = (u16*)(ws + WS_XSWZ);
    u16*   hswz  = (u16*)(ws + WS_HSWZ);
    float* hlast = (float*)(ws + WS_HLAST);

    // slot 0 = h_0 = 0 (t=0 skips tag check). Slots t>=1 keep harness poison
    // 0xAA whose tag lsb is 0 -> never validates before the producer's store.
    hipMemsetAsync(hswz, 0, B_DIM * H_DIM * sizeof(u16), stream);

    prep_x<<<2048, 256, 0, stream>>>(inputs, xswz);

    (void)hipFuncSetAttribute((const void*)lstm_scan,
                              hipFuncAttributeMaxDynamicSharedMemorySize, LDS_TOTAL);
    lstm_scan<<<NWG, 512, LDS_TOTAL, stream>>>(xswz, hswz, Wih, Whh, bih, bhh, hlast);
    fc_logsoftmax<<<B_DIM, 64, 0, stream>>>(hlast, fcw, fcb, out);
}

// Round 16
// 923.998 us; speedup vs baseline: 4.1542x; 4.1542x over previous
//
#include <hip/hip_runtime.h>
#include <hip/hip_bf16.h>

typedef unsigned short u16;
typedef unsigned int u32;
typedef unsigned long long u64;
typedef __attribute__((ext_vector_type(8))) short short8;
typedef __attribute__((ext_vector_type(4))) float floatx4;

#define I_DIM 256
#define H_DIM 1024
#define B_DIM 64
#define T_DIM 256
#define C_DIM 60
#define NWG   128
#define UPW   8      // hidden units per WG
#define BSTR  20     // pacc row stride (dwords): 16B-aligned, conflict-free pointwise
#define PACE  5      // post-publish visibility sleep, units of s_sleep(8) (~0.21us)
                     // FIXED at 5: r19 (adaptive) and r21 (structural-gap) both
                     // proved gaps below visibility+skew trade cheap sleep for
                     // expensive repair storms. Do not trim.

// LDS layout (bytes)
#define LDS_W_OFF    0        // 2*40*4*16 frags * 16B = 81920
#define LDS_BIAS_OFF 81920    // 32*4 = 128
#define LDS_PACC_OFF 82048    // 4 streams * 2 bufs * 64 rows * 20 dw * 4B = 40960
#define LDS_FLAG_OFF 123008   // 4 ints
#define LDS_TOTAL    123040

// workspace layout (bytes)
#define WS_XSWZ   0u          // T*B*I bf16 = 8388608
#define WS_HSWZ   8388608u    // 256 slots * 64*1024 bf16 = 33554432 (never reused)
#define WS_HLAST  41943040u   // 64*1024 f32 = 262144

#define LSBM 0x0001000100010001ull

__device__ __forceinline__ u16 f2bf(float f) {
    u32 u = __float_as_uint(f);
    u32 r = (u + 0x7fffu + ((u >> 16) & 1u)) >> 16;
    return (u16)r;
}
__device__ __forceinline__ float fsig(float x) { return 1.0f / (1.0f + __expf(-x)); }
__device__ __forceinline__ float ftanh(float x) { return 2.0f * fsig(2.0f * x) - 1.0f; }

union hfrag { short8 s; u64 q[2]; };

// ---------------------------------------------------------------------------
// Pre-swizzle inputs [B][T][I] fp32 -> xswz[t] bf16 in MFMA-A-fragment layout:
// 16B unit index (per t): ((mt*8 + s)*4 + q)*16 + m  holds A[b=mt*16+m][k=s*32+q*8 .. +7]
// ---------------------------------------------------------------------------
extern "C" __global__ void prep_x(const float* __restrict__ in, u16* __restrict__ xswz) {
    int o = blockIdx.x * 256 + threadIdx.x;           // octet index, 524288 total
    int m = o & 15, q = (o >> 4) & 3, s = (o >> 6) & 7, mt = (o >> 9) & 3, t = o >> 11;
    int b = mt * 16 + m, k = s * 32 + q * 8;
    const float* src = in + ((size_t)(b * T_DIM + t)) * I_DIM + k;
    float4 v0 = *(const float4*)src;
    float4 v1 = *(const float4*)(src + 4);
    short8 val;
    val[0] = (short)f2bf(v0.x); val[1] = (short)f2bf(v0.y);
    val[2] = (short)f2bf(v0.z); val[3] = (short)f2bf(v0.w);
    val[4] = (short)f2bf(v1.x); val[5] = (short)f2bf(v1.y);
    val[6] = (short)f2bf(v1.z); val[7] = (short)f2bf(v1.w);
    *(short8*)(xswz + (size_t)o * 8) = val;
}

// ---------------------------------------------------------------------------
// Persistent LSTM scan (r25 = r22 = r16, the converged operating point).
// 512-thread WGs = 8 waves = 4 INDEPENDENT 2-wave streams per CU, one
// stream per batch-pipeline of 16. Waves 2s,2s+1 map to different SIMDs, so
// each SIMD hosts 2 waves of 2 DIFFERENT streams: when one stream
// stalls/sleeps on the recurrence round-trip, the other issues.
// Per stream per step:
//   4 x-MFMA (issued pre-tag-check) -> tag-check h frags (in-band per-u16
//   tags, tag=(t%13)+1, never 0=poison; throttled agent-scope repair) ->
//   16 h-MFMA -> pacc[t&1] (stream-private dbuf) -> LDS-atomic monotonic
//   rendezvous (2 waves; no WG-wide barrier in the loop) -> pointwise
//   (c in regs) -> ack-free tagged 2B publish -> issue x(t+1) loads ->
//   FIXED PACE sleep (~1.07us store-visibility margin) -> issue h(t+1)
//   loads. Slot-per-step hswz keeps stale L2 hits structurally impossible.
// Session-exhausted alternatives: gate variants (r10-r13), slot pipelining
// (r14/r15), deeper TLP (r17/r18), adaptive pace (r19), phase stagger
// (r20), structural sub-pipeline (r21), single-wave streams (r23/r24 --
// VGPR-infeasible: compiler caps arch VGPRs at 128 regardless of
// launch_bounds; a[40] spills to 4GB of scratch traffic). The per-step
// chain is a genuine cross-device serial recurrence: publish->MALL-visible
// + margin + fetch flight + compute + rendezvous. The visibility+margin
// term is irreducible without XCD-local exchange, which the W capacity
// wall (10.5MB bf16 >> 4MB L2/XCD, >> 5MB LDS/XCD) forbids.
// ---------------------------------------------------------------------------
extern "C" __global__ void __launch_bounds__(512, 2) lstm_scan(
    const u16* __restrict__ xswz, u16* hswz,
    const float* __restrict__ Wih, const float* __restrict__ Whh,
    const float* __restrict__ bih, const float* __restrict__ bhh,
    float* hlast)
{
    extern __shared__ char lds[];
    u16*   Wlds = (u16*)(lds + LDS_W_OFF);
    float* bias = (float*)(lds + LDS_BIAS_OFF);
    float* pacc = (float*)(lds + LDS_PACC_OFF);
    int*   sbf  = (int*)(lds + LDS_FLAG_OFF);

    const int j    = blockIdx.x;
    const int tid  = threadIdx.x;
    const int lane = tid & 63;
    const int w    = tid >> 6;
    const int s    = w >> 1;      // stream = pipeline 0..3
    const int ws   = w & 1;       // wave within stream

    // ---- stage W slice into LDS, bf16, B-swizzled:
    // unit wu = ((nt*40 + sg)*4 + q)*16 + nn  holds W[r(nt,nn)][sg*32+q*8 .. +7]
    for (int i = 0; i < 10; ++i) {
        int wu = tid + i * 512;
        int nn = wu & 15, q = (wu >> 4) & 3, rest = wu >> 6;
        int sg = rest % 40, nt = rest / 40;
        int n = nt * 16 + nn;
        int g = n >> 3, uu = n & 7;
        int r = g * H_DIM + j * UPW + uu;
        int kb = sg * 32 + q * 8;
        const float* src = (kb < I_DIM) ? (Wih + (size_t)r * I_DIM + kb)
                                        : (Whh + (size_t)r * H_DIM + (kb - I_DIM));
        short8 val;
        #pragma unroll
        for (int e = 0; e < 8; ++e) val[e] = (short)f2bf(src[e]);
        *(short8*)(Wlds + (size_t)wu * 8) = val;
    }
    if (tid < 32) {
        int n = tid, g = n >> 3, uu = n & 7;
        int r = g * H_DIM + j * UPW + uu;
        bias[n] = bih[r] + bhh[r];
    }
    if (tid < 4) sbf[tid] = 0;
    __syncthreads();   // last WG-wide barrier in the kernel

    const int m16 = lane & 15, q4 = lane >> 4;
    const int sl    = ws * 64 + lane;   // 0..127 within stream
    const int pw_pm = sl >> 3;          // batch-in-16
    const int pw_uu = sl & 7;           // hidden unit within WG's 8
    float creg = 0.0f;                  // c state for this lane's item
    float* pacc_s = pacc + s * (2 * 64 * BSTR);
    int*   flag   = sbf + s;

    // A-frags: ss 0..3 = x (sg = ws*4+ss), ss 4..19 = h (sgh = ws*16+ss-4)
    hfrag a[20];

    // ---- prologue: loads for t=0 (slot 0 = h_0 = 0, no tag check at t=0)
    #pragma unroll
    for (int ss = 0; ss < 4; ++ss) {
        int sg = ws * 4 + ss;
        a[ss].s = *(const short8*)(xswz
            + (size_t)(((s * 8 + sg) * 4 + q4) * 16 + m16) * 8);
    }
    #pragma unroll
    for (int ss = 4; ss < 20; ++ss) {
        int sgh = ws * 16 + (ss - 4);
        a[ss].s = *(const short8*)(hswz
            + (size_t)(((s * 32 + sgh) * 4 + q4) * 16 + m16) * 8);
    }

    for (int t = 0; t < T_DIM; ++t) {
        const u16* hbase = hswz + (size_t)t * (B_DIM * H_DIM);   // fresh slot
        u16*       hnext = hswz + (size_t)(t + 1) * (B_DIM * H_DIM);
        const u16* xnext = xswz + (size_t)(t + 1) * (B_DIM * I_DIM);
        const int  En    = (t % 13) + 1;          // tag nibble, never 0
        const u64  Eq    = (u64)(En & 1) | ((u64)((En >> 1) & 1) << 16)
                         | ((u64)((En >> 2) & 1) << 32) | ((u64)((En >> 3) & 1) << 48);
        const int  Ep    = ((t + 1) % 13) + 1;

        // ---- x part: 8 MFMAs while h loads (still in flight) arrive
        floatx4 acc[2];
        acc[0] = (floatx4){0.f, 0.f, 0.f, 0.f};
        acc[1] = (floatx4){0.f, 0.f, 0.f, 0.f};
        #pragma unroll
        for (int ss = 0; ss < 4; ++ss) {
            int sg = ws * 4 + ss;
            #pragma unroll
            for (int nt = 0; nt < 2; ++nt) {
                short8 bv = *(const short8*)(Wlds
                    + (size_t)(((nt * 40 + sg) * 4 + q4) * 16 + m16) * 8);
                acc[nt] = __builtin_amdgcn_mfma_f32_16x16x32_bf16(
                    a[ss].s, bv, acc[nt], 0, 0, 0);
            }
        }

        // ---- validate h-frag tags; throttled agent-scope repair
        if (t > 0) {
            u32 mk = 0;
            #pragma unroll
            for (int ss = 4; ss < 20; ++ss)
                if ((((a[ss].q[0] ^ Eq) | (a[ss].q[1] ^ Eq)) & LSBM) != 0)
                    mk |= 1u << ss;
            int rounds = 0;
            while (__any(mk != 0)) {
                ++rounds;
                #pragma unroll
                for (int ss = 4; ss < 20; ++ss)
                    if ((mk >> ss) & 1) {
                        int sgh = ws * 16 + (ss - 4);
                        const u64* pp = (const u64*)hbase
                            + (size_t)(((s * 32 + sgh) * 4 + q4) * 16 + m16) * 2;
                        a[ss].q[0] = __hip_atomic_load(pp,     __ATOMIC_RELAXED, __HIP_MEMORY_SCOPE_AGENT);
                        a[ss].q[1] = __hip_atomic_load(pp + 1, __ATOMIC_RELAXED, __HIP_MEMORY_SCOPE_AGENT);
                    }
                #pragma unroll
                for (int ss = 4; ss < 20; ++ss)
                    if (((mk >> ss) & 1) &&
                        ((((a[ss].q[0] ^ Eq) | (a[ss].q[1] ^ Eq)) & LSBM) == 0))
                        mk &= ~(1u << ss);
                if (__any(mk != 0)) {
                    if (rounds < 4) __builtin_amdgcn_s_sleep(4);
                    else            __builtin_amdgcn_s_sleep(16);
                }
            }
        }

        // ---- h part: 32 MFMAs (16 h-sg x 2 ntiles)
        #pragma unroll
        for (int ss = 4; ss < 20; ++ss) {
            int sg = 8 + ws * 16 + (ss - 4);
            #pragma unroll
            for (int nt = 0; nt < 2; ++nt) {
                short8 bv = *(const short8*)(Wlds
                    + (size_t)(((nt * 40 + sg) * 4 + q4) * 16 + m16) * 8);
                acc[nt] = __builtin_amdgcn_mfma_f32_16x16x32_bf16(
                    a[ss].s, bv, acc[nt], 0, 0, 0);
            }
        }

        // ---- K-partials to stream-private pacc[t&1] (transposed)
        float* pc = pacc_s + (t & 1) * (64 * BSTR);
        #pragma unroll
        for (int nt = 0; nt < 2; ++nt)
            *(floatx4*)(pc + (ws * 32 + nt * 16 + m16) * BSTR + q4 * 4) = acc[nt];

        // ---- stream sub-barrier (monotonic LDS counter, 2 waves)
        asm volatile("s_waitcnt lgkmcnt(0)" ::: "memory");
        if (lane == 0)
            __hip_atomic_fetch_add(flag, 1, __ATOMIC_RELAXED,
                                   __HIP_MEMORY_SCOPE_WORKGROUP);
        {
            const int tgt = 2 * (t + 1);
            while (__hip_atomic_load(flag, __ATOMIC_RELAXED,
                                     __HIP_MEMORY_SCOPE_WORKGROUP) < tgt)
                __builtin_amdgcn_s_sleep(1);
        }
        asm volatile("" ::: "memory");

        // ---- pointwise: reduce 2 wave-partials, gates, c/h; tagged publish
        {
            float sv[4];
            #pragma unroll
            for (int g = 0; g < 4; ++g) {
                sv[g] = bias[g * 8 + pw_uu]
                      + pc[(g * 8 + pw_uu) * BSTR + pw_pm]
                      + pc[(32 + g * 8 + pw_uu) * BSTR + pw_pm];
            }
            float ig = fsig(sv[0]), fg = fsig(sv[1]), gg = ftanh(sv[2]), og = fsig(sv[3]);
            float c = fg * creg + ig * gg;
            creg = c;
            float h = og * ftanh(c);
            if (t == T_DIM - 1) {
                hlast[(size_t)(s * 16 + pw_pm) * H_DIM + j * UPW + pw_uu] = h;
            } else {
                u16 hb16 = (u16)((f2bf(h) & 0xFFFEu) | ((u32)(Ep >> (pw_uu & 3)) & 1u));
                // unit octet ((s*32 + (j>>2))*4 + (j&3))*16 + pm, elem uu
                u16* dst = hnext
                    + (size_t)((s * 32 + (j >> 2)) * 4 + (j & 3)) * 128 + sl;
                __hip_atomic_store(dst, hb16, __ATOMIC_RELAXED,
                                   __HIP_MEMORY_SCOPE_AGENT);
            }
        }
        asm volatile("" ::: "memory");

        // ---- issue next step's loads: x now (tag-free), h after the
        // visibility sleep (sleep is free: co-streams use the SIMD)
        if (t + 1 < T_DIM) {
            #pragma unroll
            for (int ss = 0; ss < 4; ++ss) {
                int sg = ws * 4 + ss;
                a[ss].s = *(const short8*)(xnext
                    + (size_t)(((s * 8 + sg) * 4 + q4) * 16 + m16) * 8);
            }
            for (int p = 0; p < PACE; ++p) __builtin_amdgcn_s_sleep(8);
            #pragma unroll
            for (int ss = 4; ss < 20; ++ss) {
                int sgh = ws * 16 + (ss - 4);
                a[ss].s = *(const short8*)(hnext
                    + (size_t)(((s * 32 + sgh) * 4 + q4) * 16 + m16) * 8);
            }
        }
    }
}

// ---------------------------------------------------------------------------
// FC + log_softmax: one wave per batch row. logits[b][c] = h.fc_w[c] + fc_b[c]
// ---------------------------------------------------------------------------
extern "C" __global__ void fc_logsoftmax(const float* __restrict__ hlast,
                                         const float* __restrict__ fcw,
                                         const float* __restrict__ fcb,
                                         float* __restrict__ out)
{
    int b = blockIdx.x, c = threadIdx.x;  // 64 threads, 1 wave
    float acc = 0.0f;
    if (c < C_DIM) {
        const float* wr = fcw + (size_t)c * H_DIM;
        const float* hr = hlast + (size_t)b * H_DIM;
        for (int k = 0; k < H_DIM; k += 4) {
            float4 hv = *(const float4*)(hr + k);
            float4 wv = *(const float4*)(wr + k);
            acc += hv.x * wv.x + hv.y * wv.y + hv.z * wv.z + hv.w * wv.w;
        }
        acc += fcb[c];
    }
    float logit = (c < C_DIM) ? acc : -1e30f;
    float mx = logit;
    #pragma unroll
    for (int off = 32; off; off >>= 1) mx = fmaxf(mx, __shfl_xor(mx, off));
    float e = (c < C_DIM) ? expf(logit - mx) : 0.0f;
    float sum = e;
    #pragma unroll
    for (int off = 32; off; off >>= 1) sum += __shfl_xor(sum, off);
    if (c < C_DIM) out[b * C_DIM + c] = logit - mx - logf(sum);
}

extern "C" void kernel_launch(void* const* d_in, const int* in_sizes, int n_in,
                              void* d_out, int out_size, void* d_ws, size_t ws_size,
                              hipStream_t stream)
{
    const float* inputs = (const float*)d_in[0];
    const float* Wih    = (const float*)d_in[1];
    const float* Whh    = (const float*)d_in[2];
    const float* bih    = (const float*)d_in[3];
    const float* bhh    = (const float*)d_in[4];
    const float* fcw    = (const float*)d_in[5];
    const float* fcb    = (const float*)d_in[6];
    float* out = (float*)d_out;

    char* ws = (char*)d_ws;
    u16*   xswz  = (u16*)(ws + WS_XSWZ);
    u16*   hswz  = (u16*)(ws + WS_HSWZ);
    float* hlast = (float*)(ws + WS_HLAST);

    // slot 0 = h_0 = 0 (t=0 skips tag check). Slots t>=1 keep harness poison
    // 0xAA whose tag lsb is 0 -> never validates before the producer's store.
    hipMemsetAsync(hswz, 0, B_DIM * H_DIM * sizeof(u16), stream);

    prep_x<<<2048, 256, 0, stream>>>(inputs, xswz);

    (void)hipFuncSetAttribute((const void*)lstm_scan,
                              hipFuncAttributeMaxDynamicSharedMemorySize, LDS_TOTAL);
    lstm_scan<<<NWG, 512, LDS_TOTAL, stream>>>(xswz, hswz, Wih, Whh, bih, bhh, hlast);
    fc_logsoftmax<<<B_DIM, 64, 0, stream>>>(hlast, fcw, fcb, out);
}